// Round 2
// baseline (185.931 us; speedup 1.0000x reference)
//
#include <hip/hip_runtime.h>
#include <math.h>

// Problem constants (from reference setup_inputs)
#define BB 8
#define CC 192
#define HH 128
#define WW 128
#define RPT 16   // rows per thread (8 row-streams x 16 = 128 rows per block)

struct RowReg { float l; float4 v; float r; };

__device__ __forceinline__ RowReg load_row(const float* __restrict__ xp,
                                           int g, int col, int wg) {
    float4 v;
    if (g >= 0 && g < HH) {
        v = *(const float4*)(xp + g * WW + col);
    } else {
        v = make_float4(0.0f, 0.0f, 0.0f, 0.0f);
    }
    // Horizontal neighbors from adjacent lanes (wave-level, DPP/permute).
    float l = __shfl_up(v.w, 1);
    float r = __shfl_down(v.x, 1);
    RowReg rr;
    rr.l = (wg == 0)  ? 0.0f : l;   // w = -1 halo (zero padding)
    rr.r = (wg == 31) ? 0.0f : r;   // w = 128 halo
    rr.v = v;
    return rr;
}

__device__ __forceinline__ float col9(float a0, float a1, float a2,
                                      float b0, float b1, float b2,
                                      float c0, float c1, float c2,
                                      float th, const float* kk) {
    float m;
    m = fmaf(th, kk[0], a0);
    m = fmaxf(m, fmaf(th, kk[1], a1));
    m = fmaxf(m, fmaf(th, kk[2], a2));
    m = fmaxf(m, fmaf(th, kk[3], b0));
    m = fmaxf(m, fmaf(th, kk[4], b1));
    m = fmaxf(m, fmaf(th, kk[5], b2));
    m = fmaxf(m, fmaf(th, kk[6], c0));
    m = fmaxf(m, fmaf(th, kk[7], c1));
    m = fmaxf(m, fmaf(th, kk[8], c2));
    return m;
}

__global__ __launch_bounds__(256) void dynmorph_kernel(
    const float* __restrict__ x,      // [B, C, H, W]
    const float* __restrict__ kern,   // [C, 9]
    const float* __restrict__ gw,     // [C]
    const float* __restrict__ gb,     // [C]
    float* __restrict__ out)          // [B, C, H, W]
{
    const int tid  = threadIdx.x;
    const int lane = tid & 63;
    const int wg   = lane & 31;             // column group: cols 4*wg .. 4*wg+3
    const int rs   = (tid >> 6) * 2 + (lane >> 5);  // row-stream 0..7
    const int col  = wg * 4;
    const int r0   = rs * RPT;

    const int bc = blockIdx.x;              // b*C + c
    const int c  = bc % CC;

    const float* xp = x   + (size_t)bc * (HH * WW);
    float*       op = out + (size_t)bc * (HH * WW);

    float kk[9];
#pragma unroll
    for (int i = 0; i < 9; ++i) kk[i] = kern[c * 9 + i];
    const float gwc = gw[c];
    const float gbc = gb[c];

    // Rolling 3-row window: A = row g-1, B = row g, C = row g+1
    RowReg A = load_row(xp, r0 - 1, col, wg);
    RowReg B = load_row(xp, r0,     col, wg);

#pragma unroll 4
    for (int g = 0; g < RPT; ++g) {
        const int gr = r0 + g;
        RowReg C = load_row(xp, gr + 1, col, wg);

        // theta from the CENTER row (B)
        float t0 = 1.0f / (1.0f + __expf(-fmaf(B.v.x, gwc, gbc)));
        float t1 = 1.0f / (1.0f + __expf(-fmaf(B.v.y, gwc, gbc)));
        float t2 = 1.0f / (1.0f + __expf(-fmaf(B.v.z, gwc, gbc)));
        float t3 = 1.0f / (1.0f + __expf(-fmaf(B.v.w, gwc, gbc)));

        float4 o;
        o.x = col9(A.l,   A.v.x, A.v.y,
                   B.l,   B.v.x, B.v.y,
                   C.l,   C.v.x, C.v.y, t0, kk);
        o.y = col9(A.v.x, A.v.y, A.v.z,
                   B.v.x, B.v.y, B.v.z,
                   C.v.x, C.v.y, C.v.z, t1, kk);
        o.z = col9(A.v.y, A.v.z, A.v.w,
                   B.v.y, B.v.z, B.v.w,
                   C.v.y, C.v.z, C.v.w, t2, kk);
        o.w = col9(A.v.z, A.v.w, A.r,
                   B.v.z, B.v.w, B.r,
                   C.v.z, C.v.w, C.r,   t3, kk);

        *(float4*)(op + gr * WW + col) = o;

        A = B;
        B = C;
    }
}

extern "C" void kernel_launch(void* const* d_in, const int* in_sizes, int n_in,
                              void* d_out, int out_size, void* d_ws, size_t ws_size,
                              hipStream_t stream) {
    const float* x    = (const float*)d_in[0];
    const float* kern = (const float*)d_in[1];
    const float* gw   = (const float*)d_in[2];
    const float* gb   = (const float*)d_in[3];
    float* out        = (float*)d_out;

    dim3 grid(BB * CC);   // 1536 blocks, one per (b, c) image
    dim3 block(256);
    dynmorph_kernel<<<grid, block, 0, stream>>>(x, kern, gw, gb, out);
}

// Round 3
// 185.563 us; speedup vs baseline: 1.0020x; 1.0020x over previous
//
#include <hip/hip_runtime.h>
#include <math.h>

// Problem constants (from reference setup_inputs)
#define BB 8
#define CC 192
#define HH 128
#define WW 128
#define RPT 8    // rows per thread; block covers 64 rows x 128 cols, grid.y=2 halves

__device__ __forceinline__ float col9(float a0, float a1, float a2,
                                      float b0, float b1, float b2,
                                      float c0, float c1, float c2,
                                      float th, const float* kk) {
    float m;
    m = fmaf(th, kk[0], a0);
    m = fmaxf(m, fmaf(th, kk[1], a1));
    m = fmaxf(m, fmaf(th, kk[2], a2));
    m = fmaxf(m, fmaf(th, kk[3], b0));
    m = fmaxf(m, fmaf(th, kk[4], b1));
    m = fmaxf(m, fmaf(th, kk[5], b2));
    m = fmaxf(m, fmaf(th, kk[6], c0));
    m = fmaxf(m, fmaf(th, kk[7], c1));
    m = fmaxf(m, fmaf(th, kk[8], c2));
    return m;
}

__global__ __launch_bounds__(256) void dynmorph_kernel(
    const float* __restrict__ x,      // [B, C, H, W]
    const float* __restrict__ kern,   // [C, 9]
    const float* __restrict__ gw,     // [C]
    const float* __restrict__ gb,     // [C]
    float* __restrict__ out)          // [B, C, H, W]
{
    const int tid  = threadIdx.x;
    const int lane = tid & 63;
    const int wg   = lane & 31;                      // column group: cols 4*wg..4*wg+3
    const int rs   = (tid >> 6) * 2 + (lane >> 5);   // row-stream 0..7
    const int col  = wg * 4;
    const int r0   = blockIdx.y * (RPT * 8) + rs * RPT;

    const int bc = blockIdx.x;                       // b*C + c  (block-uniform)
    const int c  = bc % CC;

    const float* xp = x   + (size_t)bc * (HH * WW);
    float*       op = out + (size_t)bc * (HH * WW);

    // Block-uniform coefficients -> SGPRs (scalar loads)
    float kk[9];
#pragma unroll
    for (int i = 0; i < 9; ++i) kk[i] = kern[c * 9 + i];
    const float gwc = gw[c];
    const float gbc = gb[c];

    // ---- Phase 1: issue ALL 10 row loads (deep MLP) ----
    float4 v[RPT + 2];
#pragma unroll
    for (int i = 0; i < RPT + 2; ++i) {
        const int g = r0 - 1 + i;
        if (g >= 0 && g < HH) {
            v[i] = *(const float4*)(xp + g * WW + col);
        } else {
            v[i] = make_float4(0.0f, 0.0f, 0.0f, 0.0f);
        }
    }

    // ---- Phase 2: halo exchange via wave shuffles (pipelines vs loads) ----
    float lf[RPT + 2], rt[RPT + 2];
#pragma unroll
    for (int i = 0; i < RPT + 2; ++i) {
        const float l = __shfl_up(v[i].w, 1);
        const float r = __shfl_down(v[i].x, 1);
        lf[i] = (wg == 0)  ? 0.0f : l;   // w = -1 (zero pad)
        rt[i] = (wg == 31) ? 0.0f : r;   // w = 128 (zero pad)
    }

    // ---- Phase 3: compute + store, fully unrolled ----
#pragma unroll
    for (int g = 0; g < RPT; ++g) {
        const float4 A = v[g], B = v[g + 1], Cv = v[g + 2];

        const float t0 = 1.0f / (1.0f + __expf(-fmaf(B.x, gwc, gbc)));
        const float t1 = 1.0f / (1.0f + __expf(-fmaf(B.y, gwc, gbc)));
        const float t2 = 1.0f / (1.0f + __expf(-fmaf(B.z, gwc, gbc)));
        const float t3 = 1.0f / (1.0f + __expf(-fmaf(B.w, gwc, gbc)));

        float4 o;
        o.x = col9(lf[g],  A.x, A.y,
                   lf[g+1], B.x, B.y,
                   lf[g+2], Cv.x, Cv.y, t0, kk);
        o.y = col9(A.x, A.y, A.z,
                   B.x, B.y, B.z,
                   Cv.x, Cv.y, Cv.z, t1, kk);
        o.z = col9(A.y, A.z, A.w,
                   B.y, B.z, B.w,
                   Cv.y, Cv.z, Cv.w, t2, kk);
        o.w = col9(A.z, A.w, rt[g],
                   B.z, B.w, rt[g+1],
                   Cv.z, Cv.w, rt[g+2], t3, kk);

        *(float4*)(op + (r0 + g) * WW + col) = o;
    }
}

extern "C" void kernel_launch(void* const* d_in, const int* in_sizes, int n_in,
                              void* d_out, int out_size, void* d_ws, size_t ws_size,
                              hipStream_t stream) {
    const float* x    = (const float*)d_in[0];
    const float* kern = (const float*)d_in[1];
    const float* gw   = (const float*)d_in[2];
    const float* gb   = (const float*)d_in[3];
    float* out        = (float*)d_out;

    dim3 grid(BB * CC, 2);   // 3072 blocks; each covers 64 rows x 128 cols
    dim3 block(256);
    dynmorph_kernel<<<grid, block, 0, stream>>>(x, kern, gw, gb, out);
}